// Round 4
// baseline (5866.235 us; speedup 1.0000x reference)
//
#include <hip/hip_runtime.h>
#include <hip/hip_bf16.h>
#include <cstdint>
#include <cstddef>

#define HID 512
#define N_INT 131072
#define N_INIT 32768

typedef __attribute__((ext_vector_type(8))) short short8_t;
typedef __attribute__((ext_vector_type(4))) float floatx4;

__device__ __forceinline__ float bf2f(unsigned short u) {
  return __uint_as_float(((unsigned)u) << 16);
}
__device__ __forceinline__ unsigned short f2bf_rne(float x) {
  unsigned u = __float_as_uint(x);
  unsigned r = u + 0x7FFF + ((u >> 16) & 1);
  return (unsigned short)(r >> 16);
}
__device__ __forceinline__ void st_split(unsigned short* hi, unsigned short* lo,
                                         size_t off, float x) {
  unsigned short h = f2bf_rne(x);
  hi[off] = h;
  lo[off] = f2bf_rne(x - bf2f(h));
}
__device__ __forceinline__ void gl_lds16(const unsigned short* g, unsigned short* l) {
  __builtin_amdgcn_global_load_lds(
      (const __attribute__((address_space(1))) unsigned int*)g,
      (__attribute__((address_space(3))) unsigned int*)l, 16, 0, 0);
}

// ---------------------------------------------------------------------------
// Layer 0 (2 -> 512), closed-form tangents; writes bf16 hi/lo planes.
// ---------------------------------------------------------------------------
__global__ __launch_bounds__(512) void layer0_int(
    const float* __restrict__ xt, long row0, int rows,
    const float* __restrict__ W0, const float* __restrict__ b0,
    unsigned short* __restrict__ act, size_t P)
{
  long i = blockIdx.x;
  if (i >= rows) return;
  int j = threadIdx.x;
  float x = xt[(row0 + i) * 2 + 0];
  float t = xt[(row0 + i) * 2 + 1];
  float wx = W0[j];
  float wt = W0[HID + j];
  float a = fmaf(x, wx, fmaf(t, wt, b0[j]));
  float y = tanhf(a);
  float d = 1.f - y * y;
  size_t o = ((size_t)i << 9) + j;
  st_split(act + 0 * P, act + 1 * P, o, y);
  st_split(act + 2 * P, act + 3 * P, o, d * wt);
  st_split(act + 4 * P, act + 5 * P, o, -2.f * y * d * wt * wt);
  st_split(act + 6 * P, act + 7 * P, o, d * wx);
  st_split(act + 8 * P, act + 9 * P, o, -2.f * y * d * wx * wx);
}

__global__ __launch_bounds__(512) void layer0_init(
    const float* __restrict__ xt, long row0, int rows,
    const float* __restrict__ W0, const float* __restrict__ b0,
    unsigned short* __restrict__ act, size_t P)
{
  long i = blockIdx.x;
  if (i >= rows) return;
  int j = threadIdx.x;
  float x = xt[(row0 + i) * 2 + 0];
  float t = xt[(row0 + i) * 2 + 1];
  float wx = W0[j];
  float wt = W0[HID + j];
  float a = fmaf(x, wx, fmaf(t, wt, b0[j]));
  float y = tanhf(a);
  float d = 1.f - y * y;
  size_t o = ((size_t)i << 9) + j;
  st_split(act + 0 * P, act + 1 * P, o, y);
  st_split(act + 2 * P, act + 3 * P, o, d * wt);
}

// ---------------------------------------------------------------------------
// W split + pack into B-fraglet layout:
//   fraglet idx (n_tile = n>>4, k_tile = k>>5); lane = ((k>>3)&3)*16 + (n&15);
//   elem j = k&7.  One fraglet = 64 lanes x 8 ushorts = 1KB, contiguous.
// ---------------------------------------------------------------------------
__global__ __launch_bounds__(512) void wsplit(
    const float* __restrict__ W,
    unsigned short* __restrict__ WfH, unsigned short* __restrict__ WfL)
{
  int n = blockIdx.x;
  int k = threadIdx.x;
  float w = W[(size_t)k * HID + n];
  size_t o = ((((size_t)(n >> 4) * 16 + (k >> 5)) * 64
               + ((k >> 3) & 3) * 16 + (n & 15)) << 3) + (k & 7);
  st_split(WfH, WfL, o, w);
}

// ---------------------------------------------------------------------------
// Fused NS-stream split-bf16 MFMA GEMM + tanh-coupling epilogue.
// 512 thr = 8 waves (4m x 2n); block tile 64x128; wave tile 16x64 per stream.
// A: LDS double-buffered, 128B rows [hi q0..q3 | lo q0..q3], slot XOR-swizzle.
// B: direct per-lane-coalesced register loads from pre-packed W fraglets (L2).
// C = Ah@Wh + Ah@Wl + Al@Wh (fp32 accum) per stream, W shared across streams.
// ---------------------------------------------------------------------------
template <int NS>
__global__ __launch_bounds__(512, 1) void gemm_mfma(
    const unsigned short* __restrict__ inp,   // 2*NS planes of P elems
    const unsigned short* __restrict__ WfH,   // fraglet-packed 512x512
    const unsigned short* __restrict__ WfL,
    const float* __restrict__ bias,
    unsigned short* __restrict__ outp,        // 2*NS planes
    size_t P, int nwg)
{
  __shared__ unsigned short Asm[2][NS][64][64];

  const int bid = blockIdx.x;
  // XCD-grouped order (nwg multiple of 8): 4 n-blocks of an m-panel are
  // consecutive on one XCD -> A panel staged from L2 after first touch.
  const int o = (bid & 7) * (nwg >> 3) + (bid >> 3);
  const long bm = (long)(o >> 2) << 6;
  const int bn = (o & 3) << 7;

  const int tid = threadIdx.x;
  const int lane = tid & 63;
  const int wv = tid >> 6;   // 0..7
  const int wm = wv & 3;     // 16-row quarter
  const int wn = wv >> 2;    // 64-col half

  floatx4 acc[NS][4];
#pragma unroll
  for (int s = 0; s < NS; ++s)
#pragma unroll
    for (int cf = 0; cf < 4; ++cf)
#pragma unroll
      for (int e = 0; e < 4; ++e) acc[s][cf][e] = 0.f;

  // ---- staging: wave wv stages rows [wv*8, wv*8+8) of each stream (1KB each)
  // dest lane l -> row wv*8 + (l>>3), phys slot (l&7); logical = (l&7)^(l>>3)
  const int srow = lane >> 3;
  const int sl = (lane & 7) ^ srow;   // logical slot
  const int sp = sl >> 2;             // 0=hi plane, 1=lo plane
  const int sq = sl & 3;              // k-quarter (8 ushorts)
  const size_t s_lane = ((size_t)srow << 9) + (size_t)(sq << 3);
  const unsigned short* asrc[NS];
#pragma unroll
  for (int s = 0; s < NS; ++s)
    asrc[s] = inp + (size_t)(2 * s + sp) * P + ((size_t)bm << 9)
            + ((size_t)wv << 12) + s_lane;

  // ---- A fragment read decomposition
  const int frow = lane & 15;
  const int fq = lane >> 4;               // k-quarter
  const int ph = fq ^ (frow & 7);         // physical slot (hi)
  const int Abyte = ((wm * 16 + frow) << 7) + (ph << 4);

  // ---- B fraglet base n-tiles
  const int bnt = (bn >> 4) + wn * 4;

  // ---- prologue: stage k-tile 0 into buf 0
#pragma unroll
  for (int s = 0; s < NS; ++s)
    gl_lds16(asrc[s], &Asm[0][s][wv * 8][0]);
  __syncthreads();

  for (int t = 0; t < 16; ++t) {
    const int cur = t & 1;
    if (t < 15) {
#pragma unroll
      for (int s = 0; s < NS; ++s)
        gl_lds16(asrc[s] + (t + 1) * 32, &Asm[cur ^ 1][s][wv * 8][0]);
    }
    // B fragments for this k-tile (coalesced 16B/lane from L2)
    short8_t bh[4], bl[4];
#pragma unroll
    for (int cf = 0; cf < 4; ++cf) {
      const size_t bo = ((((size_t)(bnt + cf) * 16 + t) << 6) + lane) << 3;
      bh[cf] = *(const short8_t*)(WfH + bo);
      bl[cf] = *(const short8_t*)(WfL + bo);
    }
#pragma unroll
    for (int s = 0; s < NS; ++s) {
      const char* Ap = (const char*)&Asm[cur][s][0][0];
      const short8_t ah = *(const short8_t*)(Ap + Abyte);
      const short8_t al = *(const short8_t*)(Ap + (Abyte ^ 64));
#pragma unroll
      for (int cf = 0; cf < 4; ++cf) {
        acc[s][cf] = __builtin_amdgcn_mfma_f32_16x16x32_bf16(ah, bh[cf], acc[s][cf], 0, 0, 0);
        acc[s][cf] = __builtin_amdgcn_mfma_f32_16x16x32_bf16(ah, bl[cf], acc[s][cf], 0, 0, 0);
        acc[s][cf] = __builtin_amdgcn_mfma_f32_16x16x32_bf16(al, bh[cf], acc[s][cf], 0, 0, 0);
      }
    }
    __syncthreads();
  }

  // ---- epilogue: tanh coupling + bf16 hi/lo split stores
#pragma unroll
  for (int cf = 0; cf < 4; ++cf) {
    const int col = bn + wn * 64 + cf * 16 + frow;
    const float bv = bias[col];
#pragma unroll
    for (int j = 0; j < 4; ++j) {
      const size_t row = (size_t)(bm + wm * 16 + fq * 4 + j);
      const size_t off = (row << 9) + col;
      const float a0 = acc[0][cf][j] + bv;
      const float e = __expf(2.f * a0);
      const float y = 1.f - __fdividef(2.f, e + 1.f);
      const float d = 1.f - y * y;
      const float a1 = acc[1][cf][j];
      const float o1 = d * a1;
      st_split(outp + 0 * P, outp + 1 * P, off, y);
      st_split(outp + 2 * P, outp + 3 * P, off, o1);
      if (NS == 5) {
        const float a2 = acc[2][cf][j];
        const float a3 = acc[3][cf][j];
        const float a4 = acc[4][cf][j];
        const float o2 = fmaf(-2.f * y * a1, o1, d * a2);
        const float o3 = d * a3;
        const float o4 = fmaf(-2.f * y * a3, o3, d * a4);
        st_split(outp + 4 * P, outp + 5 * P, off, o2);
        st_split(outp + 6 * P, outp + 7 * P, off, o3);
        st_split(outp + 8 * P, outp + 9 * P, off, o4);
      }
    }
  }
}

// ---------------------------------------------------------------------------
// Final layer (512 -> 1) dots + loss accumulation. One wave per point.
// ---------------------------------------------------------------------------
__global__ __launch_bounds__(256) void final_int(
    const unsigned short* __restrict__ act, size_t P,
    const float* __restrict__ W4, const float* __restrict__ f,
    const float* __restrict__ c, float* __restrict__ out,
    int rows, float scale)
{
  __shared__ float ls[4];
  int lane = threadIdx.x & 63, w = threadIdx.x >> 6;
  long i = (long)blockIdx.x * 4 + w;
  float val = 0.f;
  if (i < rows) {
    size_t ro = ((size_t)i << 9) + (lane << 3);
    short8_t h2 = *(const short8_t*)(act + 4 * P + ro);
    short8_t l2 = *(const short8_t*)(act + 5 * P + ro);
    short8_t h4 = *(const short8_t*)(act + 8 * P + ro);
    short8_t l4 = *(const short8_t*)(act + 9 * P + ro);
    float s_t = 0.f, s_x = 0.f;
#pragma unroll
    for (int j = 0; j < 8; ++j) {
      float wv4 = W4[(lane << 3) + j];
      s_t = fmaf(bf2f((unsigned short)h2[j]) + bf2f((unsigned short)l2[j]), wv4, s_t);
      s_x = fmaf(bf2f((unsigned short)h4[j]) + bf2f((unsigned short)l4[j]), wv4, s_x);
    }
#pragma unroll
    for (int off = 32; off; off >>= 1) {
      s_t += __shfl_xor(s_t, off);
      s_x += __shfl_xor(s_x, off);
    }
    if (lane == 0) {
      float c0 = c[0];
      float pred = s_t - c0 * c0 * s_x;
      float r = pred - f[i];
      val = r * r;
    }
  }
  if (lane == 0) ls[w] = val;
  __syncthreads();
  if (threadIdx.x == 0)
    atomicAdd(out + 2, scale * (ls[0] + ls[1] + ls[2] + ls[3]));
}

__global__ __launch_bounds__(256) void final_init(
    const unsigned short* __restrict__ act, size_t P,
    const float* __restrict__ W4, const float* __restrict__ b4,
    const float* __restrict__ g, const float* __restrict__ gd,
    float* __restrict__ out, int rows, float scale)
{
  __shared__ float ls0[4], ls1[4];
  int lane = threadIdx.x & 63, w = threadIdx.x >> 6;
  long i = (long)blockIdx.x * 4 + w;
  float v0 = 0.f, v1 = 0.f;
  if (i < rows) {
    size_t ro = ((size_t)i << 9) + (lane << 3);
    short8_t h0 = *(const short8_t*)(act + 0 * P + ro);
    short8_t l0 = *(const short8_t*)(act + 1 * P + ro);
    short8_t h1 = *(const short8_t*)(act + 2 * P + ro);
    short8_t l1 = *(const short8_t*)(act + 3 * P + ro);
    float su = 0.f, stt = 0.f;
#pragma unroll
    for (int j = 0; j < 8; ++j) {
      float wv4 = W4[(lane << 3) + j];
      su  = fmaf(bf2f((unsigned short)h0[j]) + bf2f((unsigned short)l0[j]), wv4, su);
      stt = fmaf(bf2f((unsigned short)h1[j]) + bf2f((unsigned short)l1[j]), wv4, stt);
    }
#pragma unroll
    for (int off = 32; off; off >>= 1) {
      su  += __shfl_xor(su, off);
      stt += __shfl_xor(stt, off);
    }
    if (lane == 0) {
      float r0 = su + b4[0] - g[i];
      float r1 = stt - gd[i];
      v0 = r0 * r0;
      v1 = r1 * r1;
    }
  }
  if (lane == 0) { ls0[w] = v0; ls1[w] = v1; }
  __syncthreads();
  if (threadIdx.x == 0) {
    atomicAdd(out + 0, scale * (ls0[0] + ls0[1] + ls0[2] + ls0[3]));
    atomicAdd(out + 1, scale * (ls1[0] + ls1[1] + ls1[2] + ls1[3]));
  }
}

// ---------------------------------------------------------------------------
extern "C" void kernel_launch(void* const* d_in, const int* in_sizes, int n_in,
                              void* d_out, int out_size, void* d_ws, size_t ws_size,
                              hipStream_t stream)
{
  const float* xt_int  = (const float*)d_in[0];
  const float* f       = (const float*)d_in[1];
  const float* xt_init = (const float*)d_in[2];
  const float* g       = (const float*)d_in[3];
  const float* gd      = (const float*)d_in[4];
  const float* W0 = (const float*)d_in[5];
  const float* b0 = (const float*)d_in[6];
  const float* W1 = (const float*)d_in[7];
  const float* b1 = (const float*)d_in[8];
  const float* W2 = (const float*)d_in[9];
  const float* b2 = (const float*)d_in[10];
  const float* W3 = (const float*)d_in[11];
  const float* b3 = (const float*)d_in[12];
  const float* W4 = (const float*)d_in[13];
  const float* b4 = (const float*)d_in[14];
  const float* c  = (const float*)d_in[15];
  float* out = (float*)d_out;

  hipMemsetAsync(out, 0, 3 * sizeof(float), stream);

  unsigned short* wsp = (unsigned short*)d_ws;
  const size_t WT1 = (size_t)HID * HID;     // one 512x512 plane (elems)
  const size_t wtotal = 6 * WT1;            // 3 layers x {hi,lo}
  unsigned short* Wt = wsp;

  long maxRc = (long)((ws_size / 2 - wtotal) / (20 * HID)); // rows for 2x10 planes
  long Rc = 128;
  while (Rc * 2 <= maxRc && Rc < 8192) Rc <<= 1;
  size_t P = (size_t)Rc * HID;
  unsigned short* bufA = wsp + wtotal;
  unsigned short* bufB = bufA + 10 * P;

  wsplit<<<HID, HID, 0, stream>>>(W1, Wt + 0 * WT1, Wt + 1 * WT1);
  wsplit<<<HID, HID, 0, stream>>>(W2, Wt + 2 * WT1, Wt + 3 * WT1);
  wsplit<<<HID, HID, 0, stream>>>(W3, Wt + 4 * WT1, Wt + 5 * WT1);

  const float sc_f = 0.5f / (float)N_INT;
  const float sc_i = 0.5f / (float)N_INIT;

  // ---- interior pass (5 streams) ----
  for (long i0 = 0; i0 < N_INT; i0 += Rc) {
    long rem = N_INT - i0;
    int rows = (int)(rem < Rc ? rem : Rc);
    layer0_int<<<rows, HID, 0, stream>>>(xt_int, i0, rows, W0, b0, bufA, P);
    int nwg = (rows / 64) * 4;
    gemm_mfma<5><<<nwg, 512, 0, stream>>>(bufA, Wt + 0 * WT1, Wt + 1 * WT1, b1, bufB, P, nwg);
    gemm_mfma<5><<<nwg, 512, 0, stream>>>(bufB, Wt + 2 * WT1, Wt + 3 * WT1, b2, bufA, P, nwg);
    gemm_mfma<5><<<nwg, 512, 0, stream>>>(bufA, Wt + 4 * WT1, Wt + 5 * WT1, b3, bufB, P, nwg);
    final_int<<<(rows + 3) / 4, 256, 0, stream>>>(bufB, P, W4, f + i0, c, out, rows, sc_f);
  }

  // ---- init pass (2 streams) ----
  for (long i0 = 0; i0 < N_INIT; i0 += Rc) {
    long rem = N_INIT - i0;
    int rows = (int)(rem < Rc ? rem : Rc);
    layer0_init<<<rows, HID, 0, stream>>>(xt_init, i0, rows, W0, b0, bufA, P);
    int nwg = (rows / 64) * 4;
    gemm_mfma<2><<<nwg, 512, 0, stream>>>(bufA, Wt + 0 * WT1, Wt + 1 * WT1, b1, bufB, P, nwg);
    gemm_mfma<2><<<nwg, 512, 0, stream>>>(bufB, Wt + 2 * WT1, Wt + 3 * WT1, b2, bufA, P, nwg);
    gemm_mfma<2><<<nwg, 512, 0, stream>>>(bufA, Wt + 4 * WT1, Wt + 5 * WT1, b3, bufB, P, nwg);
    final_init<<<(rows + 3) / 4, 256, 0, stream>>>(bufB, P, W4, b4, g + i0, gd + i0, out, rows, sc_i);
  }
}

// Round 5
// 4817.507 us; speedup vs baseline: 1.2177x; 1.2177x over previous
//
#include <hip/hip_runtime.h>
#include <hip/hip_bf16.h>
#include <cstdint>
#include <cstddef>

#define HID 512
#define N_INT 131072
#define N_INIT 32768

typedef __attribute__((ext_vector_type(8))) short short8_t;
typedef __attribute__((ext_vector_type(4))) float floatx4;

__device__ __forceinline__ float bf2f(unsigned short u) {
  return __uint_as_float(((unsigned)u) << 16);
}
__device__ __forceinline__ unsigned short f2bf_rne(float x) {
  unsigned u = __float_as_uint(x);
  unsigned r = u + 0x7FFF + ((u >> 16) & 1);
  return (unsigned short)(r >> 16);
}
__device__ __forceinline__ void st_split(unsigned short* hi, unsigned short* lo,
                                         size_t off, float x) {
  unsigned short h = f2bf_rne(x);
  hi[off] = h;
  lo[off] = f2bf_rne(x - bf2f(h));
}
__device__ __forceinline__ void gl_lds16(const unsigned short* g, unsigned short* l) {
  __builtin_amdgcn_global_load_lds(
      (const __attribute__((address_space(1))) unsigned int*)g,
      (__attribute__((address_space(3))) unsigned int*)l, 16, 0, 0);
}

// ---------------------------------------------------------------------------
// Layer 0 (2 -> 512), closed-form tangents; writes bf16 hi/lo planes.
// ---------------------------------------------------------------------------
__global__ __launch_bounds__(512) void layer0_int(
    const float* __restrict__ xt, long row0, int rows,
    const float* __restrict__ W0, const float* __restrict__ b0,
    unsigned short* __restrict__ act, size_t P)
{
  long i = blockIdx.x;
  if (i >= rows) return;
  int j = threadIdx.x;
  float x = xt[(row0 + i) * 2 + 0];
  float t = xt[(row0 + i) * 2 + 1];
  float wx = W0[j];
  float wt = W0[HID + j];
  float a = fmaf(x, wx, fmaf(t, wt, b0[j]));
  float y = tanhf(a);
  float d = 1.f - y * y;
  size_t o = ((size_t)i << 9) + j;
  st_split(act + 0 * P, act + 1 * P, o, y);
  st_split(act + 2 * P, act + 3 * P, o, d * wt);
  st_split(act + 4 * P, act + 5 * P, o, -2.f * y * d * wt * wt);
  st_split(act + 6 * P, act + 7 * P, o, d * wx);
  st_split(act + 8 * P, act + 9 * P, o, -2.f * y * d * wx * wx);
}

__global__ __launch_bounds__(512) void layer0_init(
    const float* __restrict__ xt, long row0, int rows,
    const float* __restrict__ W0, const float* __restrict__ b0,
    unsigned short* __restrict__ act, size_t P)
{
  long i = blockIdx.x;
  if (i >= rows) return;
  int j = threadIdx.x;
  float x = xt[(row0 + i) * 2 + 0];
  float t = xt[(row0 + i) * 2 + 1];
  float wx = W0[j];
  float wt = W0[HID + j];
  float a = fmaf(x, wx, fmaf(t, wt, b0[j]));
  float y = tanhf(a);
  float d = 1.f - y * y;
  size_t o = ((size_t)i << 9) + j;
  st_split(act + 0 * P, act + 1 * P, o, y);
  st_split(act + 2 * P, act + 3 * P, o, d * wt);
}

// ---------------------------------------------------------------------------
// W split + pack into B-fraglet layout:
//   fraglet idx (n_tile = n>>4, k_tile = k>>5); lane = ((k>>3)&3)*16 + (n&15);
//   elem j = k&7.  One fraglet = 64 lanes x 8 ushorts = 1KB, contiguous.
// ---------------------------------------------------------------------------
__global__ __launch_bounds__(512) void wsplit(
    const float* __restrict__ W,
    unsigned short* __restrict__ WfH, unsigned short* __restrict__ WfL)
{
  int n = blockIdx.x;
  int k = threadIdx.x;
  float w = W[(size_t)k * HID + n];
  size_t o = ((((size_t)(n >> 4) * 16 + (k >> 5)) * 64
               + ((k >> 3) & 3) * 16 + (n & 15)) << 3) + (k & 7);
  st_split(WfH, WfL, o, w);
}

// ---------------------------------------------------------------------------
// Fused NS-stream split-bf16 MFMA GEMM + tanh-coupling epilogue.
// 256 thr = 4 waves (2m x 2n); block tile 32x64; wave tile 16x32 per stream.
// A: LDS double-buffered (40KB), 128B rows [hi|lo], XOR slot swizzle.
// B: register-double-buffered fraglet loads from L2 (no LDS for B).
// Loop fully unrolled -> all buffer indices static; zero mid-loop VMEM waits:
// B(t) and A(t) were drained by the barrier ending iter t-1.
// C = Ah@Wh + Ah@Wl + Al@Wh (fp32 accum) per stream, W shared across streams.
// ---------------------------------------------------------------------------
template <int NS>
__global__ __launch_bounds__(256, 3) void gemm_mfma(
    const unsigned short* __restrict__ inp,   // 2*NS planes of P elems
    const unsigned short* __restrict__ WfH,   // fraglet-packed 512x512
    const unsigned short* __restrict__ WfL,
    const float* __restrict__ bias,
    unsigned short* __restrict__ outp,        // 2*NS planes
    size_t P, int nwg)
{
  __shared__ unsigned short Asm[2][NS][32][64];

  const int bid = blockIdx.x;
  // XCD-grouped order (nwg multiple of 8): the 8 n-blocks of an m-panel are
  // consecutive on one XCD -> A panel re-reads hit that XCD's L2.
  const int o = (bid & 7) * (nwg >> 3) + (bid >> 3);
  const long bm = (long)(o >> 3) << 5;
  const int bn = (o & 7) << 6;

  const int tid = threadIdx.x;
  const int lane = tid & 63;
  const int wv = tid >> 6;   // 0..3
  const int wm = wv >> 1;    // 16-row half
  const int wn = wv & 1;     // 32-col half

  floatx4 acc[NS][2];
#pragma unroll
  for (int s = 0; s < NS; ++s)
#pragma unroll
    for (int cf = 0; cf < 2; ++cf)
#pragma unroll
      for (int e = 0; e < 4; ++e) acc[s][cf][e] = 0.f;

  // ---- staging: wave wv stages rows [wv*8, wv*8+8) of each stream (1KB)
  // dest lane l -> row wv*8+(l>>3), phys slot (l&7); logical = (l&7)^(l>>3)
  const int srow = lane >> 3;
  const int sl = (lane & 7) ^ srow;   // logical slot
  const int sp = sl >> 2;             // 0=hi plane, 1=lo plane
  const int sq = sl & 3;              // k-quarter (8 ushorts)
  const size_t s_lane = ((size_t)srow << 9) + (size_t)(sq << 3);
  const unsigned short* asrc[NS];
#pragma unroll
  for (int s = 0; s < NS; ++s)
    asrc[s] = inp + (size_t)(2 * s + sp) * P + ((size_t)bm << 9)
            + ((size_t)wv << 12) + s_lane;

  // ---- A fragment read decomposition
  const int frow = lane & 15;
  const int fq = lane >> 4;               // k-quarter
  const int ph = fq ^ (frow & 7);         // physical slot (hi)
  const int Abyte = ((wm * 16 + frow) << 7) + (ph << 4);

  // ---- B fraglet pointers (16B/lane coalesced)
  const int bnt = (bn >> 4) + wn * 2;
  const unsigned short* bpH = WfH + ((size_t)bnt << 13) + (lane << 3);
  const unsigned short* bpL = WfL + ((size_t)bnt << 13) + (lane << 3);

  short8_t bh[2][2], bl[2][2];  // [k-parity][cf]

  // ---- prologue: stage A(0), load B(0)
#pragma unroll
  for (int s = 0; s < NS; ++s)
    gl_lds16(asrc[s], &Asm[0][s][wv * 8][0]);
#pragma unroll
  for (int cf = 0; cf < 2; ++cf) {
    bh[0][cf] = *(const short8_t*)(bpH + (cf << 13));
    bl[0][cf] = *(const short8_t*)(bpL + (cf << 13));
  }
  __syncthreads();

#pragma unroll
  for (int t = 0; t < 16; ++t) {
    const int cur = t & 1;
    if (t < 15) {
      // prefetch B(t+1) into the other register set
#pragma unroll
      for (int cf = 0; cf < 2; ++cf) {
        bh[cur ^ 1][cf] = *(const short8_t*)(bpH + (cf << 13) + ((t + 1) << 9));
        bl[cur ^ 1][cf] = *(const short8_t*)(bpL + (cf << 13) + ((t + 1) << 9));
      }
      // stage A(t+1) into the other LDS buffer
#pragma unroll
      for (int s = 0; s < NS; ++s)
        gl_lds16(asrc[s] + (t + 1) * 32, &Asm[cur ^ 1][s][wv * 8][0]);
    }
    // compute tile t (A from LDS, B from regs; both completed last barrier)
#pragma unroll
    for (int s = 0; s < NS; ++s) {
      const char* Ap = (const char*)&Asm[cur][s][0][0];
      const short8_t ah = *(const short8_t*)(Ap + Abyte);
      const short8_t al = *(const short8_t*)(Ap + (Abyte ^ 64));
#pragma unroll
      for (int cf = 0; cf < 2; ++cf) {
        acc[s][cf] = __builtin_amdgcn_mfma_f32_16x16x32_bf16(ah, bh[cur][cf], acc[s][cf], 0, 0, 0);
        acc[s][cf] = __builtin_amdgcn_mfma_f32_16x16x32_bf16(ah, bl[cur][cf], acc[s][cf], 0, 0, 0);
        acc[s][cf] = __builtin_amdgcn_mfma_f32_16x16x32_bf16(al, bh[cur][cf], acc[s][cf], 0, 0, 0);
      }
    }
    __syncthreads();
  }

  // ---- epilogue: tanh coupling + bf16 hi/lo split stores
#pragma unroll
  for (int cf = 0; cf < 2; ++cf) {
    const int col = bn + wn * 32 + cf * 16 + frow;
    const float bv = bias[col];
#pragma unroll
    for (int j = 0; j < 4; ++j) {
      const size_t row = (size_t)(bm + wm * 16 + fq * 4 + j);
      const size_t off = (row << 9) + col;
      const float a0 = acc[0][cf][j] + bv;
      const float e = __expf(2.f * a0);
      const float y = 1.f - __fdividef(2.f, e + 1.f);
      const float d = 1.f - y * y;
      const float a1 = acc[1][cf][j];
      const float o1 = d * a1;
      st_split(outp + 0 * P, outp + 1 * P, off, y);
      st_split(outp + 2 * P, outp + 3 * P, off, o1);
      if (NS == 5) {
        const float a2 = acc[2][cf][j];
        const float a3 = acc[3][cf][j];
        const float a4 = acc[4][cf][j];
        const float o2 = fmaf(-2.f * y * a1, o1, d * a2);
        const float o3 = d * a3;
        const float o4 = fmaf(-2.f * y * a3, o3, d * a4);
        st_split(outp + 4 * P, outp + 5 * P, off, o2);
        st_split(outp + 6 * P, outp + 7 * P, off, o3);
        st_split(outp + 8 * P, outp + 9 * P, off, o4);
      }
    }
  }
}

// ---------------------------------------------------------------------------
// Final layer (512 -> 1) dots + loss accumulation. One wave per point.
// ---------------------------------------------------------------------------
__global__ __launch_bounds__(256) void final_int(
    const unsigned short* __restrict__ act, size_t P,
    const float* __restrict__ W4, const float* __restrict__ f,
    const float* __restrict__ c, float* __restrict__ out,
    int rows, float scale)
{
  __shared__ float ls[4];
  int lane = threadIdx.x & 63, w = threadIdx.x >> 6;
  long i = (long)blockIdx.x * 4 + w;
  float val = 0.f;
  if (i < rows) {
    size_t ro = ((size_t)i << 9) + (lane << 3);
    short8_t h2 = *(const short8_t*)(act + 4 * P + ro);
    short8_t l2 = *(const short8_t*)(act + 5 * P + ro);
    short8_t h4 = *(const short8_t*)(act + 8 * P + ro);
    short8_t l4 = *(const short8_t*)(act + 9 * P + ro);
    float s_t = 0.f, s_x = 0.f;
#pragma unroll
    for (int j = 0; j < 8; ++j) {
      float wv4 = W4[(lane << 3) + j];
      s_t = fmaf(bf2f((unsigned short)h2[j]) + bf2f((unsigned short)l2[j]), wv4, s_t);
      s_x = fmaf(bf2f((unsigned short)h4[j]) + bf2f((unsigned short)l4[j]), wv4, s_x);
    }
#pragma unroll
    for (int off = 32; off; off >>= 1) {
      s_t += __shfl_xor(s_t, off);
      s_x += __shfl_xor(s_x, off);
    }
    if (lane == 0) {
      float c0 = c[0];
      float pred = s_t - c0 * c0 * s_x;
      float r = pred - f[i];
      val = r * r;
    }
  }
  if (lane == 0) ls[w] = val;
  __syncthreads();
  if (threadIdx.x == 0)
    atomicAdd(out + 2, scale * (ls[0] + ls[1] + ls[2] + ls[3]));
}

__global__ __launch_bounds__(256) void final_init(
    const unsigned short* __restrict__ act, size_t P,
    const float* __restrict__ W4, const float* __restrict__ b4,
    const float* __restrict__ g, const float* __restrict__ gd,
    float* __restrict__ out, int rows, float scale)
{
  __shared__ float ls0[4], ls1[4];
  int lane = threadIdx.x & 63, w = threadIdx.x >> 6;
  long i = (long)blockIdx.x * 4 + w;
  float v0 = 0.f, v1 = 0.f;
  if (i < rows) {
    size_t ro = ((size_t)i << 9) + (lane << 3);
    short8_t h0 = *(const short8_t*)(act + 0 * P + ro);
    short8_t l0 = *(const short8_t*)(act + 1 * P + ro);
    short8_t h1 = *(const short8_t*)(act + 2 * P + ro);
    short8_t l1 = *(const short8_t*)(act + 3 * P + ro);
    float su = 0.f, stt = 0.f;
#pragma unroll
    for (int j = 0; j < 8; ++j) {
      float wv4 = W4[(lane << 3) + j];
      su  = fmaf(bf2f((unsigned short)h0[j]) + bf2f((unsigned short)l0[j]), wv4, su);
      stt = fmaf(bf2f((unsigned short)h1[j]) + bf2f((unsigned short)l1[j]), wv4, stt);
    }
#pragma unroll
    for (int off = 32; off; off >>= 1) {
      su  += __shfl_xor(su, off);
      stt += __shfl_xor(stt, off);
    }
    if (lane == 0) {
      float r0 = su + b4[0] - g[i];
      float r1 = stt - gd[i];
      v0 = r0 * r0;
      v1 = r1 * r1;
    }
  }
  if (lane == 0) { ls0[w] = v0; ls1[w] = v1; }
  __syncthreads();
  if (threadIdx.x == 0) {
    atomicAdd(out + 0, scale * (ls0[0] + ls0[1] + ls0[2] + ls0[3]));
    atomicAdd(out + 1, scale * (ls1[0] + ls1[1] + ls1[2] + ls1[3]));
  }
}

// ---------------------------------------------------------------------------
extern "C" void kernel_launch(void* const* d_in, const int* in_sizes, int n_in,
                              void* d_out, int out_size, void* d_ws, size_t ws_size,
                              hipStream_t stream)
{
  const float* xt_int  = (const float*)d_in[0];
  const float* f       = (const float*)d_in[1];
  const float* xt_init = (const float*)d_in[2];
  const float* g       = (const float*)d_in[3];
  const float* gd      = (const float*)d_in[4];
  const float* W0 = (const float*)d_in[5];
  const float* b0 = (const float*)d_in[6];
  const float* W1 = (const float*)d_in[7];
  const float* b1 = (const float*)d_in[8];
  const float* W2 = (const float*)d_in[9];
  const float* b2 = (const float*)d_in[10];
  const float* W3 = (const float*)d_in[11];
  const float* b3 = (const float*)d_in[12];
  const float* W4 = (const float*)d_in[13];
  const float* b4 = (const float*)d_in[14];
  const float* c  = (const float*)d_in[15];
  float* out = (float*)d_out;

  hipMemsetAsync(out, 0, 3 * sizeof(float), stream);

  unsigned short* wsp = (unsigned short*)d_ws;
  const size_t WT1 = (size_t)HID * HID;     // one 512x512 plane (elems)
  const size_t wtotal = 6 * WT1;            // 3 layers x {hi,lo}
  unsigned short* Wt = wsp;

  long maxRc = (long)((ws_size / 2 - wtotal) / (20 * HID)); // rows for 2x10 planes
  long Rc = 128;
  while (Rc * 2 <= maxRc && Rc < 8192) Rc <<= 1;
  size_t P = (size_t)Rc * HID;
  unsigned short* bufA = wsp + wtotal;
  unsigned short* bufB = bufA + 10 * P;

  wsplit<<<HID, HID, 0, stream>>>(W1, Wt + 0 * WT1, Wt + 1 * WT1);
  wsplit<<<HID, HID, 0, stream>>>(W2, Wt + 2 * WT1, Wt + 3 * WT1);
  wsplit<<<HID, HID, 0, stream>>>(W3, Wt + 4 * WT1, Wt + 5 * WT1);

  const float sc_f = 0.5f / (float)N_INT;
  const float sc_i = 0.5f / (float)N_INIT;

  // ---- interior pass (5 streams) ----
  for (long i0 = 0; i0 < N_INT; i0 += Rc) {
    long rem = N_INT - i0;
    int rows = (int)(rem < Rc ? rem : Rc);
    layer0_int<<<rows, HID, 0, stream>>>(xt_int, i0, rows, W0, b0, bufA, P);
    int nwg = (rows / 32) * 8;
    gemm_mfma<5><<<nwg, 256, 0, stream>>>(bufA, Wt + 0 * WT1, Wt + 1 * WT1, b1, bufB, P, nwg);
    gemm_mfma<5><<<nwg, 256, 0, stream>>>(bufB, Wt + 2 * WT1, Wt + 3 * WT1, b2, bufA, P, nwg);
    gemm_mfma<5><<<nwg, 256, 0, stream>>>(bufA, Wt + 4 * WT1, Wt + 5 * WT1, b3, bufB, P, nwg);
    final_int<<<(rows + 3) / 4, 256, 0, stream>>>(bufB, P, W4, f + i0, c, out, rows, sc_f);
  }

  // ---- init pass (2 streams) ----
  for (long i0 = 0; i0 < N_INIT; i0 += Rc) {
    long rem = N_INIT - i0;
    int rows = (int)(rem < Rc ? rem : Rc);
    layer0_init<<<rows, HID, 0, stream>>>(xt_init, i0, rows, W0, b0, bufA, P);
    int nwg = (rows / 32) * 8;
    gemm_mfma<2><<<nwg, 256, 0, stream>>>(bufA, Wt + 0 * WT1, Wt + 1 * WT1, b1, bufB, P, nwg);
    gemm_mfma<2><<<nwg, 256, 0, stream>>>(bufB, Wt + 2 * WT1, Wt + 3 * WT1, b2, bufA, P, nwg);
    gemm_mfma<2><<<nwg, 256, 0, stream>>>(bufA, Wt + 4 * WT1, Wt + 5 * WT1, b3, bufB, P, nwg);
    final_init<<<(rows + 3) / 4, 256, 0, stream>>>(bufB, P, W4, b4, g + i0, gd + i0, out, rows, sc_i);
  }
}